// Round 14
// baseline (246.525 us; speedup 1.0000x reference)
//
#include <hip/hip_runtime.h>
#include <hip/hip_bf16.h>

// ---------------------------------------------------------------------------
// 3-layer GCN:
//   setup (1 kernel): feat->bf16 cast, W1/W2/W3 MFMA-pack, cursor init
//   build: privatized bucket scatter -> fill (CSR, scan folded in, deg hist)
//   perm:  counting-sort nodes by degree (deg_scan + deg_place) ->
//          waves process equal-degree nodes (kills max-degree divergence)
//   layer 1: fused register-gather (perm order) + MFMA(W1) -> h1
//   layer 2: fused gather + MFMA(W2) -> h2 in LDS -> MFMA(W3p) -> t [N,40]
//   layer 3: gather40 (perm order) + bias -> out fp32
// ---------------------------------------------------------------------------

#define PBUCK  800          // max 128-node buckets
#define CAPB   4096         // records per bucket region (mean 2046, ~45 sigma)

typedef __attribute__((ext_vector_type(8))) short short8;
typedef __attribute__((ext_vector_type(4))) float f32x4;

__device__ __forceinline__ float bflo(unsigned u) { return __uint_as_float(u << 16); }
__device__ __forceinline__ float bfhi(unsigned u) { return __uint_as_float(u & 0xffff0000u); }
__device__ __forceinline__ unsigned short f2bf(float f) {
    unsigned u = __float_as_uint(f);
    u = (u + 0x7fffu + ((u >> 16) & 1u)) >> 16;
    return (unsigned short)u;
}
__device__ __forceinline__ unsigned packbf(float a, float b) {
    return (unsigned)f2bf(a) | ((unsigned)f2bf(b) << 16);
}
__device__ __forceinline__ short8 as_short8(uint4 v) {
    union { uint4 u; short8 s; } x; x.u = v; return x.s;
}

// ---- device helpers for setup ----
__device__ __forceinline__ void packw_body(
    const float* __restrict__ W, unsigned short* __restrict__ Wp, int t)
{
    if (t >= 2048) return;
    int lane = t & 63, cg = (t >> 6) & 7, ks = t >> 9;
    int c = cg * 16 + (lane & 15);
    int kb = ks * 32 + (lane >> 4) * 8;
    unsigned short e[8];
    #pragma unroll
    for (int j = 0; j < 8; ++j) e[j] = f2bf(W[(size_t)(kb + j) * 128 + c]);
    uint4 v = make_uint4((unsigned)e[0] | ((unsigned)e[1] << 16),
                         (unsigned)e[2] | ((unsigned)e[3] << 16),
                         (unsigned)e[4] | ((unsigned)e[5] << 16),
                         (unsigned)e[6] | ((unsigned)e[7] << 16));
    *(uint4*)(Wp + (size_t)t * 8) = v;
}
__device__ __forceinline__ void packw3_body(
    const float* __restrict__ W, unsigned short* __restrict__ Wp, int t)
{
    if (t >= 768) return;
    int lane = t & 63, g = t >> 6;
    int ks = g / 3, cf = g % 3;
    int c = cf * 16 + (lane & 15);
    int kb = ks * 32 + (lane >> 4) * 8;
    unsigned short e[8];
    #pragma unroll
    for (int j = 0; j < 8; ++j)
        e[j] = (c < 40) ? f2bf(W[(size_t)(kb + j) * 40 + c]) : (unsigned short)0;
    uint4 v = make_uint4((unsigned)e[0] | ((unsigned)e[1] << 16),
                         (unsigned)e[2] | ((unsigned)e[3] << 16),
                         (unsigned)e[4] | ((unsigned)e[5] << 16),
                         (unsigned)e[6] | ((unsigned)e[7] << 16));
    *(uint4*)(Wp + (size_t)t * 8) = v;
}

// ---- setup: cast feat->bf16, pack weights, init cursors/hist/perm-tail ----
__global__ __launch_bounds__(256) void setup_kernel(
    const float* __restrict__ feat, unsigned short* __restrict__ SC,
    const float* __restrict__ W1, const float* __restrict__ W2,
    const float* __restrict__ W3,
    unsigned short* __restrict__ Wp1, unsigned short* __restrict__ Wp2,
    unsigned short* __restrict__ Wp3, int* __restrict__ pcur,
    int* __restrict__ ghist, int* __restrict__ perm,
    int n_nodes, int castBlocks, int npad)
{
    int b = blockIdx.x, tid = threadIdx.x;
    if (b < castBlocks) {
        int i = b * 256 + tid;
        if (i < n_nodes * 16) {
            const float4* p = (const float4*)(feat + (size_t)i * 8);
            float4 a = p[0], bb = p[1];
            uint4 v = make_uint4(packbf(a.x, a.y), packbf(a.z, a.w),
                                 packbf(bb.x, bb.y), packbf(bb.z, bb.w));
            *(uint4*)(SC + (size_t)i * 8) = v;
        }
        return;
    }
    int r = b - castBlocks;
    if (r < 8)       packw_body(W1, Wp1, r * 256 + tid);
    else if (r < 16) packw_body(W2, Wp2, (r - 8) * 256 + tid);
    else if (r < 19) packw3_body(W3, Wp3, (r - 16) * 256 + tid);
    else if (r < 23) { int i = (r - 19) * 256 + tid; if (i < PBUCK) pcur[i] = i * CAPB; }
    else {
        if (tid < 128) ghist[tid] = 0;
        int idx = n_nodes + tid;
        if (idx < npad) perm[idx] = 0x7fffffff;
    }
}

// ---- privatized scatter: LDS hist -> one fetch-add per (block,bucket) ----
__global__ __launch_bounds__(1024) void scatter_priv(
    const int* __restrict__ src, const int* __restrict__ dst,
    int* __restrict__ pcur, unsigned* __restrict__ rec, int n_edges)
{
    __shared__ int hist[PBUCK];
    __shared__ int base[PBUCK];
    int nb = gridDim.x;
    int chunk = (n_edges + nb - 1) / nb;
    int lo = blockIdx.x * chunk, hi = min(n_edges, lo + chunk);
    for (int i = threadIdx.x; i < PBUCK; i += 1024) hist[i] = 0;
    __syncthreads();
    for (int e = lo + threadIdx.x; e < hi; e += 1024)
        atomicAdd(&hist[dst[e] >> 7], 1);
    __syncthreads();
    for (int i = threadIdx.x; i < PBUCK; i += 1024) {
        int h = hist[i];
        base[i] = h ? atomicAdd(&pcur[i], h) : 0;
        hist[i] = 0;
    }
    __syncthreads();
    for (int e = lo + threadIdx.x; e < hi; e += 1024) {
        int d = dst[e];
        int b = d >> 7;
        int pos = base[b] + atomicAdd(&hist[b], 1);
        if (pos < (b + 1) * CAPB)
            rec[pos] = (unsigned)src[e] | ((unsigned)(d & 127) << 17);
    }
}

// ---- per-bucket fill: local prefix over buckets (scan folded), count,
//      node scan, write offs + ordered esrc, degree histogram ----
__global__ __launch_bounds__(512) void fill_local3(
    const unsigned* __restrict__ rec, const int* __restrict__ pcur,
    int* __restrict__ offs, int* __restrict__ esrc,
    int* __restrict__ ghist, int n_buckets, int n_nodes)
{
    __shared__ int cnt[128];
    __shared__ int cur[128];
    __shared__ int dh[128];
    __shared__ int wsum[8];
    __shared__ int redA[8], redL[8];
    const int b = blockIdx.x, tid = threadIdx.x;
    const int lane = tid & 63, wid = tid >> 6;

    // block-local prefix over all bucket totals
    int accL = 0, accA = 0;
    for (int i = tid; i < n_buckets; i += 512) {
        int t = min(pcur[i] - i * CAPB, CAPB);
        accA += t;
        if (i < b) accL += t;
    }
    #pragma unroll
    for (int off = 32; off; off >>= 1) {
        accA += __shfl_down(accA, off);
        accL += __shfl_down(accL, off);
    }
    if (lane == 0) { redA[wid] = accA; redL[wid] = accL; }
    if (tid < 128) { cnt[tid] = 0; dh[tid] = 0; }
    __syncthreads();
    int baseAll = 0, baseLt = 0;
    #pragma unroll
    for (int w = 0; w < 8; ++w) { baseAll += redA[w]; baseLt += redL[w]; }
    if (b == 0 && tid == 0) offs[n_nodes] = baseAll;

    const int node0 = b << 7;
    const int nN = min(128, n_nodes - node0);
    const int cbeg = b * CAPB;
    const int cend = cbeg + min(pcur[b] - cbeg, CAPB);

    // pass 1: count per node
    for (int i = cbeg + tid; i < cend; i += 512)
        atomicAdd(&cnt[rec[i] >> 17], 1);
    __syncthreads();

    // degree histogram contribution + scan over 128 counts
    if (tid < nN) atomicAdd(&dh[min(cnt[tid], 127)], 1);
    int c = (tid < 128) ? cnt[tid] : 0;
    int incl = c;
    #pragma unroll
    for (int off = 1; off < 64; off <<= 1) { int q = __shfl_up(incl, off); if (lane >= off) incl += q; }
    if (lane == 63) wsum[wid] = incl;
    __syncthreads();
    int wpre = 0;
    for (int w = 0; w < wid; ++w) wpre += wsum[w];
    int excl = wpre + incl - c;
    if (tid < nN) { offs[node0 + tid] = baseLt + excl; cur[tid] = excl; }
    if (tid < 128 && dh[tid]) atomicAdd(&ghist[tid], dh[tid]);
    __syncthreads();

    // pass 2: place
    for (int i = cbeg + tid; i < cend; i += 512) {
        unsigned r = rec[i];
        int pos = atomicAdd(&cur[r >> 17], 1);
        esrc[baseLt + pos] = (int)(r & 0x1FFFFu);
    }
}

// ---- exclusive scan over 128 degree bins -> gcur ----
__global__ __launch_bounds__(128) void deg_scan(
    const int* __restrict__ ghist, int* __restrict__ gcur)
{
    __shared__ int ws[2];
    int tid = threadIdx.x;
    int t = ghist[tid];
    int lane = tid & 63, wid = tid >> 6;
    int incl = t;
    #pragma unroll
    for (int off = 1; off < 64; off <<= 1) { int q = __shfl_up(incl, off); if (lane >= off) incl += q; }
    if (lane == 63) ws[wid] = incl;
    __syncthreads();
    int excl = (wid ? ws[0] : 0) + incl - t;
    gcur[tid] = excl;
}

// ---- counting-sort placement: perm = nodes ordered by degree ----
__global__ __launch_bounds__(256) void deg_place(
    const int* __restrict__ offs, int* __restrict__ gcur,
    int* __restrict__ perm, int n_nodes)
{
    __shared__ int dh[128];
    __shared__ int dbase[128];
    int nb = gridDim.x;
    int chunk = (n_nodes + nb - 1) / nb;
    int lo = blockIdx.x * chunk, hi = min(n_nodes, lo + chunk);
    int tid = threadIdx.x;
    if (tid < 128) dh[tid] = 0;
    __syncthreads();
    for (int n = lo + tid; n < hi; n += 256) {
        int d = min(offs[n + 1] - offs[n], 127);
        atomicAdd(&dh[d], 1);
    }
    __syncthreads();
    if (tid < 128) {
        int h = dh[tid];
        dbase[tid] = h ? atomicAdd(&gcur[tid], h) : 0;
        dh[tid] = 0;
    }
    __syncthreads();
    for (int n = lo + tid; n < hi; n += 256) {
        int d = min(offs[n + 1] - offs[n], 127);
        int pos = dbase[d] + atomicAdd(&dh[d], 1);
        perm[pos] = n;
    }
}

// ---- 4-edge-unrolled register gather body (128-wide, 16 lanes/node) ----
#define GATHER128_BODY(hk, e, end)                                          \
    while (e < end && (e & 3)) {                                            \
        uint4 v = *(const uint4*)(hk + (size_t)esrc[e] * 128);              \
        a0 += bflo(v.x); a1 += bfhi(v.x); a2 += bflo(v.y); a3 += bfhi(v.y); \
        a4 += bflo(v.z); a5 += bfhi(v.z); a6 += bflo(v.w); a7 += bfhi(v.w); \
        ++e;                                                                \
    }                                                                       \
    for (; e + 3 < end; e += 4) {                                           \
        int4 ss = *(const int4*)(esrc + e);                                 \
        uint4 v0 = *(const uint4*)(hk + (size_t)ss.x * 128);                \
        uint4 v1 = *(const uint4*)(hk + (size_t)ss.y * 128);                \
        uint4 v2 = *(const uint4*)(hk + (size_t)ss.z * 128);                \
        uint4 v3 = *(const uint4*)(hk + (size_t)ss.w * 128);                \
        a0 += (bflo(v0.x) + bflo(v1.x)) + (bflo(v2.x) + bflo(v3.x));        \
        a1 += (bfhi(v0.x) + bfhi(v1.x)) + (bfhi(v2.x) + bfhi(v3.x));        \
        a2 += (bflo(v0.y) + bflo(v1.y)) + (bflo(v2.y) + bflo(v3.y));        \
        a3 += (bfhi(v0.y) + bfhi(v1.y)) + (bfhi(v2.y) + bfhi(v3.y));        \
        a4 += (bflo(v0.z) + bflo(v1.z)) + (bflo(v2.z) + bflo(v3.z));        \
        a5 += (bfhi(v0.z) + bfhi(v1.z)) + (bfhi(v2.z) + bfhi(v3.z));        \
        a6 += (bflo(v0.w) + bflo(v1.w)) + (bflo(v2.w) + bflo(v3.w));        \
        a7 += (bfhi(v0.w) + bfhi(v1.w)) + (bfhi(v2.w) + bfhi(v3.w));        \
    }                                                                       \
    for (; e < end; ++e) {                                                  \
        uint4 v = *(const uint4*)(hk + (size_t)esrc[e] * 128);              \
        a0 += bflo(v.x); a1 += bfhi(v.x); a2 += bflo(v.y); a3 += bfhi(v.y); \
        a4 += bflo(v.z); a5 += bfhi(v.z); a6 += bflo(v.w); a7 += bfhi(v.w); \
    }

// ---- FUSED layer 1: perm-ordered register gather + MFMA(W) epilogue ----
__global__ __launch_bounds__(256, 8) void gather_gemm_f(
    const unsigned short* __restrict__ h, const int* __restrict__ offs,
    const int* __restrict__ esrc, const int* __restrict__ perm,
    const unsigned short* __restrict__ Wp, const float* __restrict__ bias,
    unsigned short* __restrict__ out, int n_nodes)
{
    __shared__ unsigned short accb[16 * 136];
    const int tid = threadIdx.x;
    const int nl = tid >> 4;
    const int k  = tid & 15;
    const int node0 = blockIdx.x * 16;
    const int node = perm[node0 + nl];

    float a0 = 0.f, a1 = 0.f, a2 = 0.f, a3 = 0.f;
    float a4 = 0.f, a5 = 0.f, a6 = 0.f, a7 = 0.f;
    if (node < n_nodes) {
        const unsigned short* hk = h + k * 8;
        int e = offs[node], end = offs[node + 1];
        GATHER128_BODY(hk, e, end)
    }
    {
        uint4 v = make_uint4(packbf(a0, a1), packbf(a2, a3),
                             packbf(a4, a5), packbf(a6, a7));
        *(uint4*)(accb + nl * 136 + k * 8) = v;
    }
    __syncthreads();

    const int w = tid >> 6, l = tid & 63;
    short8 afr[4];
    #pragma unroll
    for (int ks = 0; ks < 4; ++ks)
        afr[ks] = as_short8(*(const uint4*)(
            accb + (l & 15) * 136 + ks * 32 + (l >> 4) * 8));

    #pragma unroll
    for (int cf = 0; cf < 2; ++cf) {
        int cg = w * 2 + cf;
        int col = cg * 16 + (l & 15);
        float bb = bias[col];
        f32x4 vacc = { bb, bb, bb, bb };
        #pragma unroll
        for (int ks = 0; ks < 4; ++ks) {
            short8 bfr = as_short8(*(const uint4*)(Wp + (size_t)((ks * 8 + cg) * 64 + l) * 8));
            vacc = __builtin_amdgcn_mfma_f32_16x16x32_bf16(afr[ks], bfr, vacc, 0, 0, 0);
        }
        #pragma unroll
        for (int r = 0; r < 4; ++r) {
            int prow = perm[node0 + (l >> 4) * 4 + r];
            if (prow < n_nodes)
                out[(size_t)prow * 128 + col] = f2bf(fmaxf(vacc[r], 0.f));
        }
    }
}

// ---- FUSED layer 2+3a: perm gather + MFMA(W2) -> h2 LDS -> MFMA(W3p) -> t ----
__global__ __launch_bounds__(256, 8) void gather_gemm_ft(
    const unsigned short* __restrict__ h, const int* __restrict__ offs,
    const int* __restrict__ esrc, const int* __restrict__ perm,
    const unsigned short* __restrict__ Wp, const float* __restrict__ bias,
    const unsigned short* __restrict__ Wp3,
    unsigned short* __restrict__ tout, int n_nodes)
{
    __shared__ unsigned short accb[16 * 136];
    const int tid = threadIdx.x;
    const int nl = tid >> 4;
    const int k  = tid & 15;
    const int node0 = blockIdx.x * 16;
    const int node = perm[node0 + nl];

    float a0 = 0.f, a1 = 0.f, a2 = 0.f, a3 = 0.f;
    float a4 = 0.f, a5 = 0.f, a6 = 0.f, a7 = 0.f;
    if (node < n_nodes) {
        const unsigned short* hk = h + k * 8;
        int e = offs[node], end = offs[node + 1];
        GATHER128_BODY(hk, e, end)
    }
    {
        uint4 v = make_uint4(packbf(a0, a1), packbf(a2, a3),
                             packbf(a4, a5), packbf(a6, a7));
        *(uint4*)(accb + nl * 136 + k * 8) = v;
    }
    __syncthreads();

    // phase 1: h2 = relu(agg @ W2 + b2) in registers
    const int w = tid >> 6, l = tid & 63;
    short8 afr[4];
    #pragma unroll
    for (int ks = 0; ks < 4; ++ks)
        afr[ks] = as_short8(*(const uint4*)(
            accb + (l & 15) * 136 + ks * 32 + (l >> 4) * 8));

    f32x4 hacc[2];
    #pragma unroll
    for (int cf = 0; cf < 2; ++cf) {
        int cg = w * 2 + cf;
        float bb = bias[cg * 16 + (l & 15)];
        f32x4 vacc = { bb, bb, bb, bb };
        #pragma unroll
        for (int ks = 0; ks < 4; ++ks) {
            short8 bfr = as_short8(*(const uint4*)(Wp + (size_t)((ks * 8 + cg) * 64 + l) * 8));
            vacc = __builtin_amdgcn_mfma_f32_16x16x32_bf16(afr[ks], bfr, vacc, 0, 0, 0);
        }
        hacc[cf] = vacc;
    }

    __syncthreads();
    #pragma unroll
    for (int cf = 0; cf < 2; ++cf) {
        int col = (w * 2 + cf) * 16 + (l & 15);
        #pragma unroll
        for (int r = 0; r < 4; ++r)
            accb[((l >> 4) * 4 + r) * 136 + col] = f2bf(fmaxf(hacc[cf][r], 0.f));
    }
    __syncthreads();

    // phase 2: t = h2 @ W3 (48-col padded), 3 of 4 waves active
    if (w < 3) {
        short8 afr2[4];
        #pragma unroll
        for (int ks = 0; ks < 4; ++ks)
            afr2[ks] = as_short8(*(const uint4*)(
                accb + (l & 15) * 136 + ks * 32 + (l >> 4) * 8));
        f32x4 vacc = { 0.f, 0.f, 0.f, 0.f };
        #pragma unroll
        for (int ks = 0; ks < 4; ++ks) {
            short8 bfr = as_short8(*(const uint4*)(Wp3 + (size_t)((ks * 3 + w) * 64 + l) * 8));
            vacc = __builtin_amdgcn_mfma_f32_16x16x32_bf16(afr2[ks], bfr, vacc, 0, 0, 0);
        }
        int col = w * 16 + (l & 15);
        if (col < 40) {
            #pragma unroll
            for (int r = 0; r < 4; ++r) {
                int prow = perm[node0 + (l >> 4) * 4 + r];
                if (prow < n_nodes)
                    tout[(size_t)prow * 40 + col] = f2bf(vacc[r]);
            }
        }
    }
}

// ---- perm-ordered gather 40-wide + bias, fp32 out. 6 nodes/wave. ----
__global__ __launch_bounds__(256) void gather40v(
    const unsigned short* __restrict__ t, const int* __restrict__ offs,
    const int* __restrict__ esrc, const int* __restrict__ perm,
    const float* __restrict__ b3, float* __restrict__ out,
    int n_nodes, int npad)
{
    int lane = threadIdx.x & 63;
    int g = lane / 10;
    int k = lane - g * 10;
    int slot = blockIdx.x * 24 + (threadIdx.x >> 6) * 6 + g;
    if (g >= 6 || slot >= npad) return;
    int node = perm[slot];
    if (node >= n_nodes) return;
    float4 bv = *(const float4*)(b3 + k * 4);
    float a0 = bv.x, a1 = bv.y, a2 = bv.z, a3 = bv.w;
    int e = offs[node], end = offs[node + 1];
    while (e < end && (e & 3)) {
        uint2 v = *(const uint2*)(t + (size_t)esrc[e] * 40 + k * 4);
        a0 += bflo(v.x); a1 += bfhi(v.x); a2 += bflo(v.y); a3 += bfhi(v.y);
        ++e;
    }
    for (; e + 3 < end; e += 4) {
        int4 ss = *(const int4*)(esrc + e);
        uint2 v0 = *(const uint2*)(t + (size_t)ss.x * 40 + k * 4);
        uint2 v1 = *(const uint2*)(t + (size_t)ss.y * 40 + k * 4);
        uint2 v2 = *(const uint2*)(t + (size_t)ss.z * 40 + k * 4);
        uint2 v3 = *(const uint2*)(t + (size_t)ss.w * 40 + k * 4);
        a0 += (bflo(v0.x) + bflo(v1.x)) + (bflo(v2.x) + bflo(v3.x));
        a1 += (bfhi(v0.x) + bfhi(v1.x)) + (bfhi(v2.x) + bfhi(v3.x));
        a2 += (bflo(v0.y) + bflo(v1.y)) + (bflo(v2.y) + bflo(v3.y));
        a3 += (bfhi(v0.y) + bfhi(v1.y)) + (bfhi(v2.y) + bfhi(v3.y));
    }
    for (; e < end; ++e) {
        uint2 v = *(const uint2*)(t + (size_t)esrc[e] * 40 + k * 4);
        a0 += bflo(v.x); a1 += bfhi(v.x); a2 += bflo(v.y); a3 += bfhi(v.y);
    }
    *(float4*)(out + (size_t)node * 40 + k * 4) = make_float4(a0, a1, a2, a3);
}

extern "C" void kernel_launch(void* const* d_in, const int* in_sizes, int n_in,
                              void* d_out, int out_size, void* d_ws, size_t ws_size,
                              hipStream_t stream)
{
    const float* feat = (const float*)d_in[0];
    const int*   src  = (const int*)d_in[1];
    const int*   dst  = (const int*)d_in[2];
    const float* W1   = (const float*)d_in[3];
    const float* b1   = (const float*)d_in[4];
    const float* W2   = (const float*)d_in[5];
    const float* b2   = (const float*)d_in[6];
    const float* W3   = (const float*)d_in[7];
    const float* b3   = (const float*)d_in[8];
    float* out = (float*)d_out;

    const int n_edges = in_sizes[1];
    const int n_nodes = in_sizes[0] / 128;
    const int n_buckets = (n_nodes + 127) >> 7;
    const int fg = (n_nodes + 15) / 16;
    const int npad = fg * 16;

    // workspace layout (all linear)
    unsigned short* SC = (unsigned short*)d_ws;                    // [N,128] bf16: feat16 -> t[N,40]
    unsigned short* SD = SC + (size_t)n_nodes * 128;               // [N,128] bf16: h1
    unsigned* rec = (unsigned*)(SD + (size_t)n_nodes * 128);       // [PBUCK*CAPB]
    int*  esrc = (int*)(rec + (size_t)PBUCK * CAPB);               // [E]
    int*  offs = esrc + n_edges;                                   // [N+1]
    int*  pcur = offs + n_nodes + 1;                               // [PBUCK]
    unsigned short* Wp1 = (unsigned short*)(pcur + PBUCK);         // [2048*8]
    unsigned short* Wp2 = Wp1 + 2048 * 8;                          // [2048*8]
    unsigned short* Wp3 = Wp2 + 2048 * 8;                          // [768*8]
    int* ghist = (int*)(Wp3 + 768 * 8);                            // [128]
    int* gcur  = ghist + 128;                                      // [128]
    int* perm  = gcur + 128;                                       // [npad]

    const int castBlocks = (n_nodes * 16 + 255) / 256;

    // ---- setup + build + degree-sort perm ----
    setup_kernel<<<castBlocks + 24, 256, 0, stream>>>(
        feat, SC, W1, W2, W3, Wp1, Wp2, Wp3, pcur, ghist, perm,
        n_nodes, castBlocks, npad);
    scatter_priv<<<512, 1024, 0, stream>>>(src, dst, pcur, rec, n_edges);
    fill_local3<<<n_buckets, 512, 0, stream>>>(rec, pcur, offs, esrc, ghist,
                                               n_buckets, n_nodes);
    deg_scan<<<1, 128, 0, stream>>>(ghist, gcur);
    deg_place<<<256, 256, 0, stream>>>(offs, gcur, perm, n_nodes);

    // ---- layer 1: h1 = relu((A @ feat) @ W1 + b1) ----
    gather_gemm_f<<<fg, 256, 0, stream>>>(SC, offs, esrc, perm, Wp1, b1, SD, n_nodes);

    // ---- layer 2 + 3a: h2 = relu((A @ h1) @ W2 + b2) [LDS only]; t = h2 @ W3 ----
    gather_gemm_ft<<<fg, 256, 0, stream>>>(SD, offs, esrc, perm, Wp2, b2, Wp3, SC, n_nodes);

    // ---- layer 3b: out = (A @ t) + b3 ----
    gather40v<<<(npad + 23) / 24, 256, 0, stream>>>(SC, offs, esrc, perm, b3, out,
                                                    n_nodes, npad);
}

// Round 15
// 222.596 us; speedup vs baseline: 1.1075x; 1.1075x over previous
//
#include <hip/hip_runtime.h>
#include <hip/hip_bf16.h>

// ---------------------------------------------------------------------------
// 3-layer GCN (6 dispatches):
//   setup (1 kernel): feat->bf16 cast, W1/W2/W3 MFMA-pack, cursor init
//   build: privatized bucket scatter -> fill_local3 (CSR, bucket-scan folded)
//   layer 1: fused register-gather (CSR, 4-edge unrolled) + MFMA(W1) -> h1
//   layer 2: fused gather + MFMA(W2) -> h2 in LDS -> MFMA(W3p) -> t [N,40]
//   layer 3: gather40 (6 nodes/wave, 4-edge unrolled) + bias -> out fp32
// Linear node order (degree-sort perm regressed: broke esrc streaming).
// ---------------------------------------------------------------------------

#define PBUCK  800          // max 128-node buckets
#define CAPB   4096         // records per bucket region (mean 2046, ~45 sigma)

typedef __attribute__((ext_vector_type(8))) short short8;
typedef __attribute__((ext_vector_type(4))) float f32x4;

__device__ __forceinline__ float bflo(unsigned u) { return __uint_as_float(u << 16); }
__device__ __forceinline__ float bfhi(unsigned u) { return __uint_as_float(u & 0xffff0000u); }
__device__ __forceinline__ unsigned short f2bf(float f) {
    unsigned u = __float_as_uint(f);
    u = (u + 0x7fffu + ((u >> 16) & 1u)) >> 16;
    return (unsigned short)u;
}
__device__ __forceinline__ unsigned packbf(float a, float b) {
    return (unsigned)f2bf(a) | ((unsigned)f2bf(b) << 16);
}
__device__ __forceinline__ short8 as_short8(uint4 v) {
    union { uint4 u; short8 s; } x; x.u = v; return x.s;
}

// ---- device helpers for setup ----
__device__ __forceinline__ void packw_body(
    const float* __restrict__ W, unsigned short* __restrict__ Wp, int t)
{
    if (t >= 2048) return;
    int lane = t & 63, cg = (t >> 6) & 7, ks = t >> 9;
    int c = cg * 16 + (lane & 15);
    int kb = ks * 32 + (lane >> 4) * 8;
    unsigned short e[8];
    #pragma unroll
    for (int j = 0; j < 8; ++j) e[j] = f2bf(W[(size_t)(kb + j) * 128 + c]);
    uint4 v = make_uint4((unsigned)e[0] | ((unsigned)e[1] << 16),
                         (unsigned)e[2] | ((unsigned)e[3] << 16),
                         (unsigned)e[4] | ((unsigned)e[5] << 16),
                         (unsigned)e[6] | ((unsigned)e[7] << 16));
    *(uint4*)(Wp + (size_t)t * 8) = v;
}
__device__ __forceinline__ void packw3_body(
    const float* __restrict__ W, unsigned short* __restrict__ Wp, int t)
{
    if (t >= 768) return;
    int lane = t & 63, g = t >> 6;
    int ks = g / 3, cf = g % 3;
    int c = cf * 16 + (lane & 15);
    int kb = ks * 32 + (lane >> 4) * 8;
    unsigned short e[8];
    #pragma unroll
    for (int j = 0; j < 8; ++j)
        e[j] = (c < 40) ? f2bf(W[(size_t)(kb + j) * 40 + c]) : (unsigned short)0;
    uint4 v = make_uint4((unsigned)e[0] | ((unsigned)e[1] << 16),
                         (unsigned)e[2] | ((unsigned)e[3] << 16),
                         (unsigned)e[4] | ((unsigned)e[5] << 16),
                         (unsigned)e[6] | ((unsigned)e[7] << 16));
    *(uint4*)(Wp + (size_t)t * 8) = v;
}

// ---- setup: cast feat->bf16, pack weights, init cursors ----
__global__ __launch_bounds__(256) void setup_kernel(
    const float* __restrict__ feat, unsigned short* __restrict__ SC,
    const float* __restrict__ W1, const float* __restrict__ W2,
    const float* __restrict__ W3,
    unsigned short* __restrict__ Wp1, unsigned short* __restrict__ Wp2,
    unsigned short* __restrict__ Wp3, int* __restrict__ pcur,
    int n_nodes, int castBlocks)
{
    int b = blockIdx.x, tid = threadIdx.x;
    if (b < castBlocks) {
        int i = b * 256 + tid;
        if (i < n_nodes * 16) {
            const float4* p = (const float4*)(feat + (size_t)i * 8);
            float4 a = p[0], bb = p[1];
            uint4 v = make_uint4(packbf(a.x, a.y), packbf(a.z, a.w),
                                 packbf(bb.x, bb.y), packbf(bb.z, bb.w));
            *(uint4*)(SC + (size_t)i * 8) = v;
        }
        return;
    }
    int r = b - castBlocks;
    if (r < 8)       packw_body(W1, Wp1, r * 256 + tid);
    else if (r < 16) packw_body(W2, Wp2, (r - 8) * 256 + tid);
    else if (r < 19) packw3_body(W3, Wp3, (r - 16) * 256 + tid);
    else { int i = (r - 19) * 256 + tid; if (i < PBUCK) pcur[i] = i * CAPB; }
}

// ---- privatized scatter: LDS hist -> one fetch-add per (block,bucket) ----
__global__ __launch_bounds__(1024) void scatter_priv(
    const int* __restrict__ src, const int* __restrict__ dst,
    int* __restrict__ pcur, unsigned* __restrict__ rec, int n_edges)
{
    __shared__ int hist[PBUCK];
    __shared__ int base[PBUCK];
    int nb = gridDim.x;
    int chunk = (n_edges + nb - 1) / nb;
    int lo = blockIdx.x * chunk, hi = min(n_edges, lo + chunk);
    for (int i = threadIdx.x; i < PBUCK; i += 1024) hist[i] = 0;
    __syncthreads();
    for (int e = lo + threadIdx.x; e < hi; e += 1024)
        atomicAdd(&hist[dst[e] >> 7], 1);
    __syncthreads();
    for (int i = threadIdx.x; i < PBUCK; i += 1024) {
        int h = hist[i];
        base[i] = h ? atomicAdd(&pcur[i], h) : 0;
        hist[i] = 0;
    }
    __syncthreads();
    for (int e = lo + threadIdx.x; e < hi; e += 1024) {
        int d = dst[e];
        int b = d >> 7;
        int pos = base[b] + atomicAdd(&hist[b], 1);
        if (pos < (b + 1) * CAPB)
            rec[pos] = (unsigned)src[e] | ((unsigned)(d & 127) << 17);
    }
}

// ---- per-bucket fill: bucket-scan folded in, count, node scan, place ----
__global__ __launch_bounds__(512) void fill_local3(
    const unsigned* __restrict__ rec, const int* __restrict__ pcur,
    int* __restrict__ offs, int* __restrict__ esrc,
    int n_buckets, int n_nodes)
{
    __shared__ int cnt[128];
    __shared__ int cur[128];
    __shared__ int wsum[8];
    __shared__ int redA[8], redL[8];
    const int b = blockIdx.x, tid = threadIdx.x;
    const int lane = tid & 63, wid = tid >> 6;

    // block-local prefix over all bucket totals
    int accL = 0, accA = 0;
    for (int i = tid; i < n_buckets; i += 512) {
        int t = min(pcur[i] - i * CAPB, CAPB);
        accA += t;
        if (i < b) accL += t;
    }
    #pragma unroll
    for (int off = 32; off; off >>= 1) {
        accA += __shfl_down(accA, off);
        accL += __shfl_down(accL, off);
    }
    if (lane == 0) { redA[wid] = accA; redL[wid] = accL; }
    if (tid < 128) cnt[tid] = 0;
    __syncthreads();
    int baseAll = 0, baseLt = 0;
    #pragma unroll
    for (int w = 0; w < 8; ++w) { baseAll += redA[w]; baseLt += redL[w]; }
    if (b == 0 && tid == 0) offs[n_nodes] = baseAll;

    const int node0 = b << 7;
    const int nN = min(128, n_nodes - node0);
    const int cbeg = b * CAPB;
    const int cend = cbeg + min(pcur[b] - cbeg, CAPB);

    // pass 1: count per node
    for (int i = cbeg + tid; i < cend; i += 512)
        atomicAdd(&cnt[rec[i] >> 17], 1);
    __syncthreads();

    // scan over 128 counts
    int c = (tid < 128) ? cnt[tid] : 0;
    int incl = c;
    #pragma unroll
    for (int off = 1; off < 64; off <<= 1) { int q = __shfl_up(incl, off); if (lane >= off) incl += q; }
    if (lane == 63) wsum[wid] = incl;
    __syncthreads();
    int wpre = 0;
    for (int w = 0; w < wid; ++w) wpre += wsum[w];
    int excl = wpre + incl - c;
    if (tid < nN) { offs[node0 + tid] = baseLt + excl; cur[tid] = excl; }
    __syncthreads();

    // pass 2: place
    for (int i = cbeg + tid; i < cend; i += 512) {
        unsigned r = rec[i];
        int pos = atomicAdd(&cur[r >> 17], 1);
        esrc[baseLt + pos] = (int)(r & 0x1FFFFu);
    }
}

// ---- 4-edge-unrolled register gather body (128-wide, 16 lanes/node) ----
#define GATHER128_BODY(hk, e, end)                                          \
    while (e < end && (e & 3)) {                                            \
        uint4 v = *(const uint4*)(hk + (size_t)esrc[e] * 128);              \
        a0 += bflo(v.x); a1 += bfhi(v.x); a2 += bflo(v.y); a3 += bfhi(v.y); \
        a4 += bflo(v.z); a5 += bfhi(v.z); a6 += bflo(v.w); a7 += bfhi(v.w); \
        ++e;                                                                \
    }                                                                       \
    for (; e + 3 < end; e += 4) {                                           \
        int4 ss = *(const int4*)(esrc + e);                                 \
        uint4 v0 = *(const uint4*)(hk + (size_t)ss.x * 128);                \
        uint4 v1 = *(const uint4*)(hk + (size_t)ss.y * 128);                \
        uint4 v2 = *(const uint4*)(hk + (size_t)ss.z * 128);                \
        uint4 v3 = *(const uint4*)(hk + (size_t)ss.w * 128);                \
        a0 += (bflo(v0.x) + bflo(v1.x)) + (bflo(v2.x) + bflo(v3.x));        \
        a1 += (bfhi(v0.x) + bfhi(v1.x)) + (bfhi(v2.x) + bfhi(v3.x));        \
        a2 += (bflo(v0.y) + bflo(v1.y)) + (bflo(v2.y) + bflo(v3.y));        \
        a3 += (bfhi(v0.y) + bfhi(v1.y)) + (bfhi(v2.y) + bfhi(v3.y));        \
        a4 += (bflo(v0.z) + bflo(v1.z)) + (bflo(v2.z) + bflo(v3.z));        \
        a5 += (bfhi(v0.z) + bfhi(v1.z)) + (bfhi(v2.z) + bfhi(v3.z));        \
        a6 += (bflo(v0.w) + bflo(v1.w)) + (bflo(v2.w) + bflo(v3.w));        \
        a7 += (bfhi(v0.w) + bfhi(v1.w)) + (bfhi(v2.w) + bfhi(v3.w));        \
    }                                                                       \
    for (; e < end; ++e) {                                                  \
        uint4 v = *(const uint4*)(hk + (size_t)esrc[e] * 128);              \
        a0 += bflo(v.x); a1 += bfhi(v.x); a2 += bflo(v.y); a3 += bfhi(v.y); \
        a4 += bflo(v.z); a5 += bfhi(v.z); a6 += bflo(v.w); a7 += bfhi(v.w); \
    }

// ---- FUSED layer 1: register gather (CSR) of 16 nodes + MFMA(W) epilogue ----
__global__ __launch_bounds__(256, 8) void gather_gemm_f(
    const unsigned short* __restrict__ h, const int* __restrict__ offs,
    const int* __restrict__ esrc, const unsigned short* __restrict__ Wp,
    const float* __restrict__ bias, unsigned short* __restrict__ out,
    int n_nodes)
{
    __shared__ unsigned short accb[16 * 136];
    const int tid = threadIdx.x;
    const int nl = tid >> 4;
    const int k  = tid & 15;
    const int node = blockIdx.x * 16 + nl;

    float a0 = 0.f, a1 = 0.f, a2 = 0.f, a3 = 0.f;
    float a4 = 0.f, a5 = 0.f, a6 = 0.f, a7 = 0.f;
    if (node < n_nodes) {
        const unsigned short* hk = h + k * 8;
        int e = offs[node], end = offs[node + 1];
        GATHER128_BODY(hk, e, end)
    }
    {
        uint4 v = make_uint4(packbf(a0, a1), packbf(a2, a3),
                             packbf(a4, a5), packbf(a6, a7));
        *(uint4*)(accb + nl * 136 + k * 8) = v;
    }
    __syncthreads();

    const int w = tid >> 6, l = tid & 63;
    short8 afr[4];
    #pragma unroll
    for (int ks = 0; ks < 4; ++ks)
        afr[ks] = as_short8(*(const uint4*)(
            accb + (l & 15) * 136 + ks * 32 + (l >> 4) * 8));

    const int node0 = blockIdx.x * 16;
    #pragma unroll
    for (int cf = 0; cf < 2; ++cf) {
        int cg = w * 2 + cf;
        int col = cg * 16 + (l & 15);
        float bb = bias[col];
        f32x4 vacc = { bb, bb, bb, bb };
        #pragma unroll
        for (int ks = 0; ks < 4; ++ks) {
            short8 bfr = as_short8(*(const uint4*)(Wp + (size_t)((ks * 8 + cg) * 64 + l) * 8));
            vacc = __builtin_amdgcn_mfma_f32_16x16x32_bf16(afr[ks], bfr, vacc, 0, 0, 0);
        }
        #pragma unroll
        for (int r = 0; r < 4; ++r) {
            int row = node0 + (l >> 4) * 4 + r;
            if (row < n_nodes)
                out[(size_t)row * 128 + col] = f2bf(fmaxf(vacc[r], 0.f));
        }
    }
}

// ---- FUSED layer 2+3a: gather + MFMA(W2) -> h2 in LDS -> MFMA(W3p,48) -> t ----
__global__ __launch_bounds__(256, 8) void gather_gemm_ft(
    const unsigned short* __restrict__ h, const int* __restrict__ offs,
    const int* __restrict__ esrc, const unsigned short* __restrict__ Wp,
    const float* __restrict__ bias, const unsigned short* __restrict__ Wp3,
    unsigned short* __restrict__ tout, int n_nodes)
{
    __shared__ unsigned short accb[16 * 136];
    const int tid = threadIdx.x;
    const int nl = tid >> 4;
    const int k  = tid & 15;
    const int node = blockIdx.x * 16 + nl;

    float a0 = 0.f, a1 = 0.f, a2 = 0.f, a3 = 0.f;
    float a4 = 0.f, a5 = 0.f, a6 = 0.f, a7 = 0.f;
    if (node < n_nodes) {
        const unsigned short* hk = h + k * 8;
        int e = offs[node], end = offs[node + 1];
        GATHER128_BODY(hk, e, end)
    }
    {
        uint4 v = make_uint4(packbf(a0, a1), packbf(a2, a3),
                             packbf(a4, a5), packbf(a6, a7));
        *(uint4*)(accb + nl * 136 + k * 8) = v;
    }
    __syncthreads();

    // phase 1: h2 = relu(agg @ W2 + b2) in registers
    const int w = tid >> 6, l = tid & 63;
    short8 afr[4];
    #pragma unroll
    for (int ks = 0; ks < 4; ++ks)
        afr[ks] = as_short8(*(const uint4*)(
            accb + (l & 15) * 136 + ks * 32 + (l >> 4) * 8));

    f32x4 hacc[2];
    #pragma unroll
    for (int cf = 0; cf < 2; ++cf) {
        int cg = w * 2 + cf;
        float bb = bias[cg * 16 + (l & 15)];
        f32x4 vacc = { bb, bb, bb, bb };
        #pragma unroll
        for (int ks = 0; ks < 4; ++ks) {
            short8 bfr = as_short8(*(const uint4*)(Wp + (size_t)((ks * 8 + cg) * 64 + l) * 8));
            vacc = __builtin_amdgcn_mfma_f32_16x16x32_bf16(afr[ks], bfr, vacc, 0, 0, 0);
        }
        hacc[cf] = vacc;
    }

    __syncthreads();
    #pragma unroll
    for (int cf = 0; cf < 2; ++cf) {
        int col = (w * 2 + cf) * 16 + (l & 15);
        #pragma unroll
        for (int r = 0; r < 4; ++r)
            accb[((l >> 4) * 4 + r) * 136 + col] = f2bf(fmaxf(hacc[cf][r], 0.f));
    }
    __syncthreads();

    // phase 2: t = h2 @ W3 (48-col padded), 3 of 4 waves active
    if (w < 3) {
        short8 afr2[4];
        #pragma unroll
        for (int ks = 0; ks < 4; ++ks)
            afr2[ks] = as_short8(*(const uint4*)(
                accb + (l & 15) * 136 + ks * 32 + (l >> 4) * 8));
        f32x4 vacc = { 0.f, 0.f, 0.f, 0.f };
        #pragma unroll
        for (int ks = 0; ks < 4; ++ks) {
            short8 bfr = as_short8(*(const uint4*)(Wp3 + (size_t)((ks * 3 + w) * 64 + l) * 8));
            vacc = __builtin_amdgcn_mfma_f32_16x16x32_bf16(afr2[ks], bfr, vacc, 0, 0, 0);
        }
        int col = w * 16 + (l & 15);
        if (col < 40) {
            const int node0 = blockIdx.x * 16;
            #pragma unroll
            for (int r = 0; r < 4; ++r) {
                int row = node0 + (l >> 4) * 4 + r;
                if (row < n_nodes)
                    tout[(size_t)row * 40 + col] = f2bf(vacc[r]);
            }
        }
    }
}

// ---- gather 40-wide bf16 rows + bias, fp32 out. 6 nodes/wave, 4-unrolled. ----
__global__ __launch_bounds__(256) void gather40v(
    const unsigned short* __restrict__ t, const int* __restrict__ offs,
    const int* __restrict__ esrc, const float* __restrict__ b3,
    float* __restrict__ out, int n_nodes)
{
    int lane = threadIdx.x & 63;
    int g = lane / 10;
    int k = lane - g * 10;
    int node = blockIdx.x * 24 + (threadIdx.x >> 6) * 6 + g;
    if (g >= 6 || node >= n_nodes) return;
    float4 bv = *(const float4*)(b3 + k * 4);
    float a0 = bv.x, a1 = bv.y, a2 = bv.z, a3 = bv.w;
    int e = offs[node], end = offs[node + 1];
    while (e < end && (e & 3)) {
        uint2 v = *(const uint2*)(t + (size_t)esrc[e] * 40 + k * 4);
        a0 += bflo(v.x); a1 += bfhi(v.x); a2 += bflo(v.y); a3 += bfhi(v.y);
        ++e;
    }
    for (; e + 3 < end; e += 4) {
        int4 ss = *(const int4*)(esrc + e);
        uint2 v0 = *(const uint2*)(t + (size_t)ss.x * 40 + k * 4);
        uint2 v1 = *(const uint2*)(t + (size_t)ss.y * 40 + k * 4);
        uint2 v2 = *(const uint2*)(t + (size_t)ss.z * 40 + k * 4);
        uint2 v3 = *(const uint2*)(t + (size_t)ss.w * 40 + k * 4);
        a0 += (bflo(v0.x) + bflo(v1.x)) + (bflo(v2.x) + bflo(v3.x));
        a1 += (bfhi(v0.x) + bfhi(v1.x)) + (bfhi(v2.x) + bfhi(v3.x));
        a2 += (bflo(v0.y) + bflo(v1.y)) + (bflo(v2.y) + bflo(v3.y));
        a3 += (bfhi(v0.y) + bfhi(v1.y)) + (bfhi(v2.y) + bfhi(v3.y));
    }
    for (; e < end; ++e) {
        uint2 v = *(const uint2*)(t + (size_t)esrc[e] * 40 + k * 4);
        a0 += bflo(v.x); a1 += bfhi(v.x); a2 += bflo(v.y); a3 += bfhi(v.y);
    }
    *(float4*)(out + (size_t)node * 40 + k * 4) = make_float4(a0, a1, a2, a3);
}

extern "C" void kernel_launch(void* const* d_in, const int* in_sizes, int n_in,
                              void* d_out, int out_size, void* d_ws, size_t ws_size,
                              hipStream_t stream)
{
    const float* feat = (const float*)d_in[0];
    const int*   src  = (const int*)d_in[1];
    const int*   dst  = (const int*)d_in[2];
    const float* W1   = (const float*)d_in[3];
    const float* b1   = (const float*)d_in[4];
    const float* W2   = (const float*)d_in[5];
    const float* b2   = (const float*)d_in[6];
    const float* W3   = (const float*)d_in[7];
    const float* b3   = (const float*)d_in[8];
    float* out = (float*)d_out;

    const int n_edges = in_sizes[1];
    const int n_nodes = in_sizes[0] / 128;
    const int n_buckets = (n_nodes + 127) >> 7;
    const int fg = (n_nodes + 15) / 16;

    // workspace layout (all linear)
    unsigned short* SC = (unsigned short*)d_ws;                    // [N,128] bf16: feat16 -> t[N,40]
    unsigned short* SD = SC + (size_t)n_nodes * 128;               // [N,128] bf16: h1
    unsigned* rec = (unsigned*)(SD + (size_t)n_nodes * 128);       // [PBUCK*CAPB]
    int*  esrc = (int*)(rec + (size_t)PBUCK * CAPB);               // [E]
    int*  offs = esrc + n_edges;                                   // [N+1]
    int*  pcur = offs + n_nodes + 1;                               // [PBUCK]
    unsigned short* Wp1 = (unsigned short*)(pcur + PBUCK);         // [2048*8]
    unsigned short* Wp2 = Wp1 + 2048 * 8;                          // [2048*8]
    unsigned short* Wp3 = Wp2 + 2048 * 8;                          // [768*8]

    const int castBlocks = (n_nodes * 16 + 255) / 256;

    // ---- setup + build ----
    setup_kernel<<<castBlocks + 23, 256, 0, stream>>>(
        feat, SC, W1, W2, W3, Wp1, Wp2, Wp3, pcur, n_nodes, castBlocks);
    scatter_priv<<<512, 1024, 0, stream>>>(src, dst, pcur, rec, n_edges);
    fill_local3<<<n_buckets, 512, 0, stream>>>(rec, pcur, offs, esrc,
                                               n_buckets, n_nodes);

    // ---- layer 1: h1 = relu((A @ feat) @ W1 + b1) ----
    gather_gemm_f<<<fg, 256, 0, stream>>>(SC, offs, esrc, Wp1, b1, SD, n_nodes);

    // ---- layer 2 + 3a: h2 = relu((A @ h1) @ W2 + b2) [LDS only]; t = h2 @ W3 ----
    gather_gemm_ft<<<fg, 256, 0, stream>>>(SD, offs, esrc, Wp2, b2, Wp3, SC, n_nodes);

    // ---- layer 3b: out = (A @ t) + b3 ----
    gather40v<<<(n_nodes + 23) / 24, 256, 0, stream>>>(SC, offs, esrc, b3, out, n_nodes);
}